// Round 2
// baseline (297.473 us; speedup 1.0000x reference)
//
#include <hip/hip_runtime.h>

// Causal linear attention (elu+1 feature map) — single-kernel decoupled-lookback.
// N=4, L=4096, H=12, D=M=64.  L split into 16 partitions of 256 rows (4 chunks
// of 64).  One block per (n,h,partition), 768 blocks total:
//   Phase 1 : partition KV^T total (fp32 MFMA over 4 chunks) + Ksum total.
//   Publish : agent-scope stores of own total + release flag.
//   Lookback: sum totals of partitions 0..p-1 (parallel, no serial chain).
//   Walk    : per chunk  A = Qf Kf^T (masked); O = Amask V + Qf S;
//             z = rowsum(A) + Qf.Ksum;  S += KV^T(chunk).
// Q is consumed straight from global into registers (wave w owns rows 16w+nn),
// so LDS = 4 tiles = 37.4KB -> 4 blocks/CU (16 waves/CU).
// Deadlock-safe: blocks wait only on lower block IDs and grid(768) <= resident
// capacity (4/CU * 256CU = 1024), so all blocks are co-resident.

#define NBATCH 4
#define LSEQ   4096
#define NHEAD  12
#define DDIM   64
#define LSTRIDE (NHEAD * DDIM)
#define NH     (NBATCH * NHEAD)
#define EPSF   1e-6f
#define CHUNK  64
#define NUMC   (LSEQ / CHUNK)
#define PPART  16               // partitions per sequence
#define CPP    (NUMC / PPART)   // chunks per partition = 4
#define SB     72               // LDS row stride in shorts (16B-aligned frags)
#define PAYLOAD (DDIM * DDIM + DDIM)   // per-partition ws floats: 4096 kv + 64 ksum

typedef __attribute__((ext_vector_type(8))) short bf16x8;
typedef __attribute__((ext_vector_type(4))) float f32x4;

__device__ __forceinline__ float phi(float x) { return x > 0.f ? x + 1.f : __expf(x); }
__device__ __forceinline__ float4 phi4(float4 x) {
    float4 r = {phi(x.x), phi(x.y), phi(x.z), phi(x.w)};
    return r;
}

__device__ __forceinline__ unsigned short f2bf(float x) {
    union { float f; unsigned u; } v; v.f = x;
    unsigned r = v.u + 0x7fffu + ((v.u >> 16) & 1u);   // RNE
    return (unsigned short)(r >> 16);
}
__device__ __forceinline__ float bf2f(short s) {
    union { float f; unsigned u; } v; v.u = ((unsigned)(unsigned short)s) << 16;
    return v.f;
}
__device__ __forceinline__ uint2 pack4(float4 a) {
    uint2 r;
    r.x = (unsigned)f2bf(a.x) | ((unsigned)f2bf(a.y) << 16);
    r.y = (unsigned)f2bf(a.z) | ((unsigned)f2bf(a.w) << 16);
    return r;
}
__device__ __forceinline__ bf16x8 packbf8(float4 a, float4 b) {
    union { bf16x8 v; uint2 u[2]; } r;
    r.u[0] = pack4(a);
    r.u[1] = pack4(b);
    return r.v;
}

// 4x4 fp32 transpose among lanes {lane^16, lane^32}.
__device__ __forceinline__ float4 xpose4(float4 x, int lane) {
    const bool b0 = (lane >> 4) & 1, b1 = (lane >> 5) & 1;
    float s0 = b0 ? x.x : x.y;
    float s1 = b0 ? x.z : x.w;
    s0 = __shfl_xor(s0, 16);
    s1 = __shfl_xor(s1, 16);
    float4 y;
    if (b0) { y.x = s0;  y.y = x.y; y.z = s1;  y.w = x.w; }
    else    { y.x = x.x; y.y = s0;  y.z = x.z; y.w = s1;  }
    float t0 = b1 ? y.x : y.z;
    float t1 = b1 ? y.y : y.w;
    t0 = __shfl_xor(t0, 32);
    t1 = __shfl_xor(t1, 32);
    float4 z;
    if (b1) { z.x = t0;  z.y = t1;  z.z = y.z; z.w = y.w; }
    else    { z.x = y.x; z.y = y.y; z.z = t0;  z.w = t1;  }
    return z;
}

// ---------------------------------------------------------------------------
__global__ __launch_bounds__(256) void k_init(int* __restrict__ flags) {
    flags[blockIdx.x * 256 + threadIdx.x] = 0;
}

// ---------------------------------------------------------------------------
__global__ __launch_bounds__(256, 4) void k_la(const float* __restrict__ qin,
                                               const float* __restrict__ kin,
                                               const float* __restrict__ vin,
                                               float* __restrict__ ws,
                                               float* __restrict__ out) {
    __shared__ short sK [64 * SB];   // K rows (phi,bf16); reused as Amask in walk
    __shared__ short sKT[64 * SB];   // [d][l]
    __shared__ short sVT[64 * SB];   // [m][l]
    __shared__ short sST[64 * SB];   // [m][d] bf16 mirror of running S^T
    __shared__ float sKs[64];
    __shared__ float sZq[64];

    const int b = blockIdx.x, seq = b / PPART, p = b % PPART;
    const int n0 = seq / NHEAD, h0 = seq % NHEAD;
    const int t = threadIdx.x;
    const int lane = t & 63, w = t >> 6;
    const int nn = lane & 15, qq = lane >> 4;
    const int c4 = nn << 2;
    int* flags = (int*)(ws + (size_t)NH * PPART * PAYLOAD);

    float4 kreg[4], vreg[4];
    auto LOADKV = [&](int cc) {
        const int gb = ((n0 * LSEQ + (p * CPP + cc) * CHUNK) * NHEAD + h0) * DDIM;
#pragma unroll
        for (int rep = 0; rep < 4; ++rep) {
            const int r16 = rep * 16 + 4 * w + qq;
            kreg[rep] = *(const float4*)(kin + gb + r16 * LSTRIDE + c4);
            vreg[rep] = *(const float4*)(vin + gb + r16 * LSTRIDE + c4);
        }
    };
    auto LOADQ = [&](int cc, bf16x8& o0, bf16x8& o1) {
        const float* qp = qin + ((n0 * LSEQ + (p * CPP + cc) * CHUNK) * NHEAD + h0) * DDIM
                        + (16 * w + nn) * LSTRIDE;
        float4 a = phi4(*(const float4*)(qp + qq * 8));
        float4 bq = phi4(*(const float4*)(qp + qq * 8 + 4));
        float4 cq = phi4(*(const float4*)(qp + 32 + qq * 8));
        float4 dq = phi4(*(const float4*)(qp + 32 + qq * 8 + 4));
        o0 = packbf8(a, bq);
        o1 = packbf8(cq, dq);
    };

    // ---- Phase 1: own partition KV^T total + Ksum total ----
    f32x4 Sown[4] = {{0,0,0,0},{0,0,0,0},{0,0,0,0},{0,0,0,0}};
    float ksOwn = 0.f;
    LOADKV(0);
    for (int cc = 0; cc < CPP; ++cc) {
#pragma unroll
        for (int rep = 0; rep < 4; ++rep) {
            const int l0 = rep * 16 + 4 * w;
            float4 kp = phi4(kreg[rep]);
            float4 kt = xpose4(kp, lane);
            *(uint2*)(sKT + (c4 + qq) * SB + l0) = pack4(kt);
            float4 vt = xpose4(vreg[rep], lane);
            *(uint2*)(sVT + (c4 + qq) * SB + l0) = pack4(vt);
        }
        __syncthreads();
        if (cc + 1 < CPP) LOADKV(cc + 1);
        const int rowM = 16 * w + nn;
        bf16x8 af0 = *(const bf16x8*)(sVT + rowM * SB + qq * 8);
        bf16x8 af1 = *(const bf16x8*)(sVT + rowM * SB + 32 + qq * 8);
#pragma unroll
        for (int ct = 0; ct < 4; ++ct) {
            bf16x8 bf0 = *(const bf16x8*)(sKT + (16 * ct + nn) * SB + qq * 8);
            bf16x8 bf1 = *(const bf16x8*)(sKT + (16 * ct + nn) * SB + 32 + qq * 8);
            Sown[ct] = __builtin_amdgcn_mfma_f32_16x16x32_bf16(af0, bf0, Sown[ct], 0, 0, 0);
            Sown[ct] = __builtin_amdgcn_mfma_f32_16x16x32_bf16(af1, bf1, Sown[ct], 0, 0, 0);
            if (ct == w) {   // wave-uniform: Ksum for d-band 16w..16w+15
                float s = 0.f;
#pragma unroll
                for (int j = 0; j < 8; ++j) s += bf2f(bf0[j]) + bf2f(bf1[j]);
                s += __shfl_xor(s, 16);
                s += __shfl_xor(s, 32);
                ksOwn += s;
            }
        }
        __syncthreads();
    }

    // ---- Publish own total (agent scope: cross-XCD visible) ----
    float* myb = ws + (size_t)b * PAYLOAD;
#pragma unroll
    for (int ct = 0; ct < 4; ++ct)
#pragma unroll
        for (int r = 0; r < 4; ++r)
            __hip_atomic_store(&myb[(16 * w + 4 * qq + r) * DDIM + 16 * ct + nn],
                               Sown[ct][r], __ATOMIC_RELAXED, __HIP_MEMORY_SCOPE_AGENT);
    if (qq == 0)
        __hip_atomic_store(&myb[DDIM * DDIM + 16 * w + nn], ksOwn,
                           __ATOMIC_RELAXED, __HIP_MEMORY_SCOPE_AGENT);
    __syncthreads();   // per-wave vmcnt(0): all payload stores complete
    if (t == 0)
        __hip_atomic_store(&flags[b], 1, __ATOMIC_RELEASE, __HIP_MEMORY_SCOPE_AGENT);

    // ---- Lookback: exclusive prefix = sum of predecessors' totals ----
    f32x4 Sreg[4] = {{0,0,0,0},{0,0,0,0},{0,0,0,0},{0,0,0,0}};
    float ksp = 0.f;
    if (p > 0) {
        if (t < p) {
            int* fl = &flags[seq * PPART + t];
            while (__hip_atomic_load(fl, __ATOMIC_ACQUIRE, __HIP_MEMORY_SCOPE_AGENT) == 0)
                __builtin_amdgcn_s_sleep(8);
        }
        __syncthreads();
        for (int j = 0; j < p; ++j) {
            float* tb = ws + (size_t)(seq * PPART + j) * PAYLOAD;
#pragma unroll
            for (int ct = 0; ct < 4; ++ct)
#pragma unroll
                for (int r = 0; r < 4; ++r)
                    Sreg[ct][r] += __hip_atomic_load(
                        &tb[(16 * w + 4 * qq + r) * DDIM + 16 * ct + nn],
                        __ATOMIC_RELAXED, __HIP_MEMORY_SCOPE_AGENT);
        }
        if (t < 64) {
            for (int j = 0; j < p; ++j)
                ksp += __hip_atomic_load(
                    ws + (size_t)(seq * PPART + j) * PAYLOAD + DDIM * DDIM + t,
                    __ATOMIC_RELAXED, __HIP_MEMORY_SCOPE_AGENT);
        }
    }
    if (t < 64) sKs[t] = ksp;
    // bf16 mirror of exclusive-prefix S^T  (sST writes guarded by next barrier)
#pragma unroll
    for (int ct = 0; ct < 4; ++ct)
#pragma unroll
        for (int r = 0; r < 4; ++r)
            sST[(16 * w + 4 * qq + r) * SB + 16 * ct + nn] = (short)f2bf(Sreg[ct][r]);

    // ---- Walk: 4 chunks, outputs + running S ----
    bf16x8 qf0, qf1, qfn0, qfn1;
    LOADKV(0);
    LOADQ(0, qf0, qf1);
    for (int cc = 0; cc < CPP; ++cc) {
        const int gbase = ((n0 * LSEQ + (p * CPP + cc) * CHUNK) * NHEAD + h0) * DDIM;
        // ---- stage chunk into LDS (K rows + K^T + V^T) ----
#pragma unroll
        for (int rep = 0; rep < 4; ++rep) {
            const int row = rep * 16 + 4 * w + qq;
            const int l0 = rep * 16 + 4 * w;
            float4 kp = phi4(kreg[rep]);
            *(uint2*)(sK + row * SB + c4) = pack4(kp);
            float4 kt = xpose4(kp, lane);
            *(uint2*)(sKT + (c4 + qq) * SB + l0) = pack4(kt);
            float4 vt = xpose4(vreg[rep], lane);
            *(uint2*)(sVT + (c4 + qq) * SB + l0) = pack4(vt);
        }
        __syncthreads();   // S1

        // ---- Phase A: A = Qf Kf^T, mask + rowsum; zq from Ksum prefix ----
        const int rowA = 16 * w + nn;
        float am[4][4];
        float zrow[4] = {0.f, 0.f, 0.f, 0.f};
#pragma unroll
        for (int ct = 0; ct < 4; ++ct) {
            bf16x8 kf0 = *(const bf16x8*)(sK + (16 * ct + nn) * SB + qq * 8);
            bf16x8 kf1 = *(const bf16x8*)(sK + (16 * ct + nn) * SB + 32 + qq * 8);
            f32x4 acc = {0.f, 0.f, 0.f, 0.f};
            acc = __builtin_amdgcn_mfma_f32_16x16x32_bf16(qf0, kf0, acc, 0, 0, 0);
            acc = __builtin_amdgcn_mfma_f32_16x16x32_bf16(qf1, kf1, acc, 0, 0, 0);
#pragma unroll
            for (int r = 0; r < 4; ++r) {
                const int ri = 16 * w + 4 * qq + r, cj = 16 * ct + nn;
                const float mval = (cj <= ri) ? acc[r] : 0.f;
                am[ct][r] = mval;
                zrow[r] += mval;
            }
        }
#pragma unroll
        for (int r = 0; r < 4; ++r) {
            float s = zrow[r];
            s += __shfl_xor(s, 1); s += __shfl_xor(s, 2);
            s += __shfl_xor(s, 4); s += __shfl_xor(s, 8);
            zrow[r] = s;
        }
        float zq = 0.f;
#pragma unroll
        for (int j = 0; j < 8; ++j) {
            zq += bf2f(qf0[j]) * sKs[qq * 8 + j];
            zq += bf2f(qf1[j]) * sKs[32 + qq * 8 + j];
        }
        zq += __shfl_xor(zq, 16);
        zq += __shfl_xor(zq, 32);

        __syncthreads();   // S2: K reads + sKs reads done
        if (qq == 0) sZq[16 * w + nn] = zq;
#pragma unroll
        for (int ct = 0; ct < 4; ++ct)
#pragma unroll
            for (int r = 0; r < 4; ++r)
                sK[(16 * w + 4 * qq + r) * SB + 16 * ct + nn] = (short)f2bf(am[ct][r]);
        __syncthreads();   // S3: Amask + sZq visible

        if (cc + 1 < CPP) {           // prefetch next chunk under B/C
            LOADKV(cc + 1);
            LOADQ(cc + 1, qfn0, qfn1);
        }

        // ---- Phases B/C + KV^T accumulate ----
        f32x4 o[4] = {{0,0,0,0},{0,0,0,0},{0,0,0,0},{0,0,0,0}};
        bf16x8 af0 = *(const bf16x8*)(sK + rowA * SB + qq * 8);
        bf16x8 af1 = *(const bf16x8*)(sK + rowA * SB + 32 + qq * 8);
        bf16x8 av0 = *(const bf16x8*)(sVT + rowA * SB + qq * 8);
        bf16x8 av1 = *(const bf16x8*)(sVT + rowA * SB + 32 + qq * 8);
        float ksc = 0.f;
#pragma unroll
        for (int ct = 0; ct < 4; ++ct) {
            bf16x8 vf0 = *(const bf16x8*)(sVT + (16 * ct + nn) * SB + qq * 8);
            bf16x8 vf1 = *(const bf16x8*)(sVT + (16 * ct + nn) * SB + 32 + qq * 8);
            o[ct] = __builtin_amdgcn_mfma_f32_16x16x32_bf16(af0, vf0, o[ct], 0, 0, 0);
            o[ct] = __builtin_amdgcn_mfma_f32_16x16x32_bf16(af1, vf1, o[ct], 0, 0, 0);
            bf16x8 sf0 = *(const bf16x8*)(sST + (16 * ct + nn) * SB + qq * 8);
            bf16x8 sf1 = *(const bf16x8*)(sST + (16 * ct + nn) * SB + 32 + qq * 8);
            o[ct] = __builtin_amdgcn_mfma_f32_16x16x32_bf16(qf0, sf0, o[ct], 0, 0, 0);
            o[ct] = __builtin_amdgcn_mfma_f32_16x16x32_bf16(qf1, sf1, o[ct], 0, 0, 0);
            bf16x8 kt0 = *(const bf16x8*)(sKT + (16 * ct + nn) * SB + qq * 8);
            bf16x8 kt1 = *(const bf16x8*)(sKT + (16 * ct + nn) * SB + 32 + qq * 8);
            Sreg[ct] = __builtin_amdgcn_mfma_f32_16x16x32_bf16(av0, kt0, Sreg[ct], 0, 0, 0);
            Sreg[ct] = __builtin_amdgcn_mfma_f32_16x16x32_bf16(av1, kt1, Sreg[ct], 0, 0, 0);
            if (ct == w) {   // chunk Ksum for d-band 16w..16w+15
                float s = 0.f;
#pragma unroll
                for (int j = 0; j < 8; ++j) s += bf2f(kt0[j]) + bf2f(kt1[j]);
                s += __shfl_xor(s, 16);
                s += __shfl_xor(s, 32);
                ksc = s;
            }
        }

#pragma unroll
        for (int r = 0; r < 4; ++r) {
            const int ri = 16 * w + 4 * qq + r;
            const float z = zrow[r] + sZq[ri] + EPSF;
            const float invz = 1.f / z;
#pragma unroll
            for (int ct = 0; ct < 4; ++ct)
                out[gbase + ri * LSTRIDE + 16 * ct + nn] = o[ct][r] * invz;
        }
        __syncthreads();   // S4: all reads of old sST / sVT / sKT / sK done
        // refresh bf16 S mirror + Ksum prefix for next chunk
#pragma unroll
        for (int ct = 0; ct < 4; ++ct)
#pragma unroll
            for (int r = 0; r < 4; ++r)
                sST[(16 * w + 4 * qq + r) * SB + 16 * ct + nn] = (short)f2bf(Sreg[ct][r]);
        if (qq == 0) sKs[16 * w + nn] += ksc;
        qf0 = qfn0;
        qf1 = qfn1;
    }
}

// ---------------------------------------------------------------------------
// Fallback (tiny ws): fully sequential per-sequence scan, fp32, no workspace.
// ---------------------------------------------------------------------------
__global__ __launch_bounds__(64) void k_seq(const float* __restrict__ qin,
                                            const float* __restrict__ kin,
                                            const float* __restrict__ vin,
                                            float* __restrict__ out) {
    const int seq = blockIdx.x;
    const int n = seq / NHEAD, h = seq % NHEAD;
    const int lane = threadIdx.x;
    float Scol[DDIM];
#pragma unroll
    for (int d = 0; d < DDIM; ++d) Scol[d] = 0.0f;
    float kc = 0.0f;
    __shared__ float qk[2 * DDIM];
    int base = (n * LSEQ * NHEAD + h) * DDIM + lane;
    for (int i = 0; i < LSEQ; ++i) {
        float qval = phi(qin[base]);
        float kval = phi(kin[base]);
        float vval = vin[base];
        kc += kval;
        float zp = qval * kc;
#pragma unroll
        for (int off = 32; off > 0; off >>= 1) zp += __shfl_xor(zp, off, 64);
        float z = zp + EPSF;
        qk[2 * lane] = kval;
        qk[2 * lane + 1] = qval;
        __syncthreads();
        const float4* qk4 = (const float4*)qk;
        float acc = 0.0f;
#pragma unroll
        for (int d2 = 0; d2 < DDIM / 2; ++d2) {
            float4 t0 = qk4[d2];
            int d = 2 * d2;
            Scol[d]     += t0.x * vval;  acc += t0.y * Scol[d];
            Scol[d + 1] += t0.z * vval;  acc += t0.w * Scol[d + 1];
        }
        out[base] = acc / z;
        base += LSTRIDE;
        __syncthreads();
    }
}

// ---------------------------------------------------------------------------
extern "C" void kernel_launch(void* const* d_in, const int* in_sizes, int n_in,
                              void* d_out, int out_size, void* d_ws, size_t ws_size,
                              hipStream_t stream) {
    const float* q = (const float*)d_in[0];
    const float* k = (const float*)d_in[1];
    const float* v = (const float*)d_in[2];
    float* out = (float*)d_out;
    float* ws  = (float*)d_ws;

    const size_t need = (size_t)NH * PPART * PAYLOAD * sizeof(float)
                      + (size_t)NH * PPART * sizeof(int);
    if (ws_size >= need) {
        int* flags = (int*)(ws + (size_t)NH * PPART * PAYLOAD);
        k_init<<<NH * PPART / 256, 256, 0, stream>>>(flags);
        k_la<<<NH * PPART, 256, 0, stream>>>(q, k, v, ws, out);
    } else {
        k_seq<<<NH, 64, 0, stream>>>(q, k, v, out);
    }
}

// Round 3
// 253.172 us; speedup vs baseline: 1.1750x; 1.1750x over previous
//
#include <hip/hip_runtime.h>

// Causal linear attention (elu+1 feature map) — partition-coarsened MFMA scheme.
// N=4, L=4096, H=12, D=M=64.  L split into 32 partitions of 128 rows (2 chunks
// of 64).  3 kernels:
//   k_psum : per-partition KV^T total (fp32 MFMA over 2 chunks) + Ksum total.
//   k_scanP: exclusive prefix scan over 32 partitions (batched loads).
//   k_fused: walks the partition's 2 chunks, running S in fp32 regs (bf16
//            mirror in LDS):  A = Qf Kf^T (masked); O = Amask V + Qf S;
//            z = rowsum(A) + Qf.Ksum;  S += KV^T(chunk).
// Q is consumed straight from global into registers (wave w owns rows 16w+nn),
// so k_fused LDS = 4 tiles = 37.4KB -> 4 blocks/CU; grid 1536 = 6 blocks/CU of
// work keeps the pipeline full (round-1's 768-block grid was occupancy-capped).

#define NBATCH 4
#define LSEQ   4096
#define NHEAD  12
#define DDIM   64
#define LSTRIDE (NHEAD * DDIM)
#define NH     (NBATCH * NHEAD)
#define EPSF   1e-6f
#define CHUNK  64
#define NUMC   (LSEQ / CHUNK)
#define PPART  32               // partitions per sequence
#define CPP    (NUMC / PPART)   // chunks per partition = 2
#define SB     72               // LDS row stride in shorts (16B-aligned frags)

typedef __attribute__((ext_vector_type(8))) short bf16x8;
typedef __attribute__((ext_vector_type(4))) float f32x4;

__device__ __forceinline__ float phi(float x) { return x > 0.f ? x + 1.f : __expf(x); }
__device__ __forceinline__ float4 phi4(float4 x) {
    float4 r = {phi(x.x), phi(x.y), phi(x.z), phi(x.w)};
    return r;
}

__device__ __forceinline__ unsigned short f2bf(float x) {
    union { float f; unsigned u; } v; v.f = x;
    unsigned r = v.u + 0x7fffu + ((v.u >> 16) & 1u);   // RNE
    return (unsigned short)(r >> 16);
}
__device__ __forceinline__ float bf2f(short s) {
    union { float f; unsigned u; } v; v.u = ((unsigned)(unsigned short)s) << 16;
    return v.f;
}
__device__ __forceinline__ uint2 pack4(float4 a) {
    uint2 r;
    r.x = (unsigned)f2bf(a.x) | ((unsigned)f2bf(a.y) << 16);
    r.y = (unsigned)f2bf(a.z) | ((unsigned)f2bf(a.w) << 16);
    return r;
}
__device__ __forceinline__ bf16x8 packbf8(float4 a, float4 b) {
    union { bf16x8 v; uint2 u[2]; } r;
    r.u[0] = pack4(a);
    r.u[1] = pack4(b);
    return r.v;
}

// 4x4 fp32 transpose among lanes {lane^16, lane^32}.
__device__ __forceinline__ float4 xpose4(float4 x, int lane) {
    const bool b0 = (lane >> 4) & 1, b1 = (lane >> 5) & 1;
    float s0 = b0 ? x.x : x.y;
    float s1 = b0 ? x.z : x.w;
    s0 = __shfl_xor(s0, 16);
    s1 = __shfl_xor(s1, 16);
    float4 y;
    if (b0) { y.x = s0;  y.y = x.y; y.z = s1;  y.w = x.w; }
    else    { y.x = x.x; y.y = s0;  y.z = x.z; y.w = s1;  }
    float t0 = b1 ? y.x : y.z;
    float t1 = b1 ? y.y : y.w;
    t0 = __shfl_xor(t0, 32);
    t1 = __shfl_xor(t1, 32);
    float4 z;
    if (b1) { z.x = t0;  z.y = t1;  z.z = y.z; z.w = y.w; }
    else    { z.x = y.x; z.y = y.y; z.z = t0;  z.w = t1;  }
    return z;
}

// ---------------------------------------------------------------------------
// Kernel 1: partition totals.  KV^T[m][d] = sum_l V[l][m] Kf[l][d] over 128
// rows (2 sub-chunks, fp32 MFMA accumulation), Ksum[d] = sum_l Kf[l][d].
// ---------------------------------------------------------------------------
__global__ __launch_bounds__(256) void k_psum(const float* __restrict__ kin,
                                              const float* __restrict__ vin,
                                              float* __restrict__ kvws,
                                              float* __restrict__ ksws) {
    __shared__ short sKT[64 * SB];   // [d][l]
    __shared__ short sVT[64 * SB];   // [m][l]
    const int b = blockIdx.x, seq = b / PPART, p = b % PPART;
    const int n0 = seq / NHEAD, h0 = seq % NHEAD;
    const int t = threadIdx.x;
    const int lane = t & 63, w = t >> 6;
    const int nn = lane & 15, qq = lane >> 4;
    const int c4 = nn << 2;

    float4 kreg[4], vreg[4];
    auto LOADKV = [&](int cc) {
        const int gb = ((n0 * LSEQ + (p * CPP + cc) * CHUNK) * NHEAD + h0) * DDIM;
#pragma unroll
        for (int rep = 0; rep < 4; ++rep) {
            const int r16 = rep * 16 + 4 * w + qq;
            kreg[rep] = *(const float4*)(kin + gb + r16 * LSTRIDE + c4);
            vreg[rep] = *(const float4*)(vin + gb + r16 * LSTRIDE + c4);
        }
    };

    f32x4 S[4] = {{0,0,0,0},{0,0,0,0},{0,0,0,0},{0,0,0,0}};
    float ks = 0.f;
    LOADKV(0);
    for (int cc = 0; cc < CPP; ++cc) {
#pragma unroll
        for (int rep = 0; rep < 4; ++rep) {
            const int l0 = rep * 16 + 4 * w;
            float4 kp = phi4(kreg[rep]);
            float4 kt = xpose4(kp, lane);
            *(uint2*)(sKT + (c4 + qq) * SB + l0) = pack4(kt);
            float4 vt = xpose4(vreg[rep], lane);
            *(uint2*)(sVT + (c4 + qq) * SB + l0) = pack4(vt);
        }
        __syncthreads();
        if (cc + 1 < CPP) LOADKV(cc + 1);   // latency hides under MFMA
        const int rowM = 16 * w + nn;
        bf16x8 af0 = *(const bf16x8*)(sVT + rowM * SB + qq * 8);
        bf16x8 af1 = *(const bf16x8*)(sVT + rowM * SB + 32 + qq * 8);
#pragma unroll
        for (int ct = 0; ct < 4; ++ct) {
            bf16x8 bf0 = *(const bf16x8*)(sKT + (16 * ct + nn) * SB + qq * 8);
            bf16x8 bf1 = *(const bf16x8*)(sKT + (16 * ct + nn) * SB + 32 + qq * 8);
            S[ct] = __builtin_amdgcn_mfma_f32_16x16x32_bf16(af0, bf0, S[ct], 0, 0, 0);
            S[ct] = __builtin_amdgcn_mfma_f32_16x16x32_bf16(af1, bf1, S[ct], 0, 0, 0);
            if (ct == w) {   // wave-uniform: Ksum for d-band 16w..16w+15
                float s = 0.f;
#pragma unroll
                for (int j = 0; j < 8; ++j) s += bf2f(bf0[j]) + bf2f(bf1[j]);
                s += __shfl_xor(s, 16);
                s += __shfl_xor(s, 32);
                ks += s;
            }
        }
        __syncthreads();
    }
    float* kvb = kvws + (size_t)b * (DDIM * DDIM);
#pragma unroll
    for (int ct = 0; ct < 4; ++ct)
#pragma unroll
        for (int r = 0; r < 4; ++r)
            kvb[(16 * w + 4 * qq + r) * DDIM + 16 * ct + nn] = S[ct][r];
    if (qq == 0) ksws[b * DDIM + 16 * w + nn] = ks;
}

// ---------------------------------------------------------------------------
// Kernel 2: exclusive prefix scan over 32 partitions, batched register loads
// (8 in flight) so latency is paid ~4x, not 32x.
// ---------------------------------------------------------------------------
__global__ __launch_bounds__(64) void k_scanP(float* __restrict__ kv,
                                              float* __restrict__ ksum) {
    const int bid = blockIdx.x;
    const int seq = bid >> 4, part16 = bid & 15;
    const int t = threadIdx.x;
    float4* base = (float4*)(kv + (size_t)seq * PPART * DDIM * DDIM) + part16 * 64 + t;
    float4 S = {0.f, 0.f, 0.f, 0.f};
    for (int b0 = 0; b0 < PPART; b0 += 8) {
        float4 x[8];
#pragma unroll
        for (int j = 0; j < 8; ++j) x[j] = base[(b0 + j) * (DDIM * DDIM / 4)];
#pragma unroll
        for (int j = 0; j < 8; ++j) {
            base[(b0 + j) * (DDIM * DDIM / 4)] = S;
            S.x += x[j].x; S.y += x[j].y; S.z += x[j].z; S.w += x[j].w;
        }
    }
    if (part16 == 0) {
        float* kb = ksum + (size_t)seq * PPART * DDIM + t;
        float s = 0.f;
        for (int b0 = 0; b0 < PPART; b0 += 8) {
            float xs[8];
#pragma unroll
            for (int j = 0; j < 8; ++j) xs[j] = kb[(b0 + j) * DDIM];
#pragma unroll
            for (int j = 0; j < 8; ++j) { kb[(b0 + j) * DDIM] = s; s += xs[j]; }
        }
    }
}

// ---------------------------------------------------------------------------
// Kernel 3: fused per-partition output.  Walks 2 chunks; S held as fp32 in
// registers (MFMA C layout), mirrored to bf16 LDS for the Qf*S matmul.
// Q is loaded straight to registers (no LDS tile).
// ---------------------------------------------------------------------------
__global__ __launch_bounds__(256, 4) void k_fused(const float* __restrict__ qin,
                                                  const float* __restrict__ kin,
                                                  const float* __restrict__ vin,
                                                  const float* __restrict__ kvws,
                                                  const float* __restrict__ ksws,
                                                  float* __restrict__ out) {
    __shared__ short sK [64 * SB];   // K rows (phi,bf16); reused as Amask
    __shared__ short sKT[64 * SB];   // [d][l]
    __shared__ short sVT[64 * SB];   // [m][l]
    __shared__ short sST[64 * SB];   // [m][d] bf16 mirror of running S^T
    __shared__ float sKs[64];
    __shared__ float sZq[64];

    const int b = blockIdx.x, seq = b / PPART, p = b % PPART;
    const int n0 = seq / NHEAD, h0 = seq % NHEAD;
    const int t = threadIdx.x;
    const int lane = t & 63, w = t >> 6;
    const int nn = lane & 15, qq = lane >> 4;
    const int c4 = nn << 2;

    float4 kreg[4], vreg[4];
    auto LOADKV = [&](int cc) {
        const int gb = ((n0 * LSEQ + (p * CPP + cc) * CHUNK) * NHEAD + h0) * DDIM;
#pragma unroll
        for (int rep = 0; rep < 4; ++rep) {
            const int r16 = rep * 16 + 4 * w + qq;
            kreg[rep] = *(const float4*)(kin + gb + r16 * LSTRIDE + c4);
            vreg[rep] = *(const float4*)(vin + gb + r16 * LSTRIDE + c4);
        }
    };
    auto LOADQ = [&](int cc, bf16x8& o0, bf16x8& o1) {
        const float* qp = qin + ((n0 * LSEQ + (p * CPP + cc) * CHUNK) * NHEAD + h0) * DDIM
                        + (16 * w + nn) * LSTRIDE;
        float4 a = phi4(*(const float4*)(qp + qq * 8));
        float4 bq = phi4(*(const float4*)(qp + qq * 8 + 4));
        float4 cq = phi4(*(const float4*)(qp + 32 + qq * 8));
        float4 dq = phi4(*(const float4*)(qp + 32 + qq * 8 + 4));
        o0 = packbf8(a, bq);
        o1 = packbf8(cq, dq);
    };

    // issue independent global loads first (latency overlaps prefix setup)
    bf16x8 qf0, qf1, qfn0, qfn1;
    LOADKV(0);
    LOADQ(0, qf0, qf1);
    if (t < 64) sKs[t] = ksws[b * DDIM + t];

    // Exclusive partition-prefix S: fp32 into registers + bf16 mirror in LDS.
    const float* Sg = kvws + (size_t)b * (DDIM * DDIM);
    f32x4 Sreg[4];
#pragma unroll
    for (int ct = 0; ct < 4; ++ct) {
#pragma unroll
        for (int r = 0; r < 4; ++r) {
            const float sv = Sg[(16 * w + 4 * qq + r) * DDIM + 16 * ct + nn];
            Sreg[ct][r] = sv;
            sST[(16 * w + 4 * qq + r) * SB + 16 * ct + nn] = (short)f2bf(sv);
        }
    }

    for (int cc = 0; cc < CPP; ++cc) {
        const int gbase = ((n0 * LSEQ + (p * CPP + cc) * CHUNK) * NHEAD + h0) * DDIM;
        // ---- stage chunk into LDS (K rows + K^T + V^T) ----
#pragma unroll
        for (int rep = 0; rep < 4; ++rep) {
            const int row = rep * 16 + 4 * w + qq;
            const int l0 = rep * 16 + 4 * w;
            float4 kp = phi4(kreg[rep]);
            *(uint2*)(sK + row * SB + c4) = pack4(kp);
            float4 kt = xpose4(kp, lane);
            *(uint2*)(sKT + (c4 + qq) * SB + l0) = pack4(kt);
            float4 vt = xpose4(vreg[rep], lane);
            *(uint2*)(sVT + (c4 + qq) * SB + l0) = pack4(vt);
        }
        __syncthreads();   // S1

        // ---- Phase A: A = Qf Kf^T, mask + rowsum; zq from Ksum prefix ----
        const int rowA = 16 * w + nn;
        float am[4][4];
        float zrow[4] = {0.f, 0.f, 0.f, 0.f};
#pragma unroll
        for (int ct = 0; ct < 4; ++ct) {
            bf16x8 kf0 = *(const bf16x8*)(sK + (16 * ct + nn) * SB + qq * 8);
            bf16x8 kf1 = *(const bf16x8*)(sK + (16 * ct + nn) * SB + 32 + qq * 8);
            f32x4 acc = {0.f, 0.f, 0.f, 0.f};
            acc = __builtin_amdgcn_mfma_f32_16x16x32_bf16(qf0, kf0, acc, 0, 0, 0);
            acc = __builtin_amdgcn_mfma_f32_16x16x32_bf16(qf1, kf1, acc, 0, 0, 0);
#pragma unroll
            for (int r = 0; r < 4; ++r) {
                const int ri = 16 * w + 4 * qq + r, cj = 16 * ct + nn;
                const float mval = (cj <= ri) ? acc[r] : 0.f;
                am[ct][r] = mval;
                zrow[r] += mval;
            }
        }
#pragma unroll
        for (int r = 0; r < 4; ++r) {
            float s = zrow[r];
            s += __shfl_xor(s, 1); s += __shfl_xor(s, 2);
            s += __shfl_xor(s, 4); s += __shfl_xor(s, 8);
            zrow[r] = s;
        }
        float zq = 0.f;
#pragma unroll
        for (int j = 0; j < 8; ++j) {
            zq += bf2f(qf0[j]) * sKs[qq * 8 + j];
            zq += bf2f(qf1[j]) * sKs[32 + qq * 8 + j];
        }
        zq += __shfl_xor(zq, 16);
        zq += __shfl_xor(zq, 32);

        __syncthreads();   // S2: K reads + sKs reads done
        if (qq == 0) sZq[16 * w + nn] = zq;
#pragma unroll
        for (int ct = 0; ct < 4; ++ct)
#pragma unroll
            for (int r = 0; r < 4; ++r)
                sK[(16 * w + 4 * qq + r) * SB + 16 * ct + nn] = (short)f2bf(am[ct][r]);
        __syncthreads();   // S3: Amask + sZq visible

        if (cc + 1 < CPP) {           // prefetch next chunk under B/C
            LOADKV(cc + 1);
            LOADQ(cc + 1, qfn0, qfn1);
        }

        // ---- Phases B/C + KV^T accumulate ----
        f32x4 o[4] = {{0,0,0,0},{0,0,0,0},{0,0,0,0},{0,0,0,0}};
        bf16x8 af0 = *(const bf16x8*)(sK + rowA * SB + qq * 8);
        bf16x8 af1 = *(const bf16x8*)(sK + rowA * SB + 32 + qq * 8);
        bf16x8 av0 = *(const bf16x8*)(sVT + rowA * SB + qq * 8);
        bf16x8 av1 = *(const bf16x8*)(sVT + rowA * SB + 32 + qq * 8);
        float ksc = 0.f;
        __builtin_amdgcn_s_setprio(1);
#pragma unroll
        for (int ct = 0; ct < 4; ++ct) {
            bf16x8 vf0 = *(const bf16x8*)(sVT + (16 * ct + nn) * SB + qq * 8);
            bf16x8 vf1 = *(const bf16x8*)(sVT + (16 * ct + nn) * SB + 32 + qq * 8);
            o[ct] = __builtin_amdgcn_mfma_f32_16x16x32_bf16(af0, vf0, o[ct], 0, 0, 0);
            o[ct] = __builtin_amdgcn_mfma_f32_16x16x32_bf16(af1, vf1, o[ct], 0, 0, 0);
            bf16x8 sf0 = *(const bf16x8*)(sST + (16 * ct + nn) * SB + qq * 8);
            bf16x8 sf1 = *(const bf16x8*)(sST + (16 * ct + nn) * SB + 32 + qq * 8);
            o[ct] = __builtin_amdgcn_mfma_f32_16x16x32_bf16(qf0, sf0, o[ct], 0, 0, 0);
            o[ct] = __builtin_amdgcn_mfma_f32_16x16x32_bf16(qf1, sf1, o[ct], 0, 0, 0);
            bf16x8 kt0 = *(const bf16x8*)(sKT + (16 * ct + nn) * SB + qq * 8);
            bf16x8 kt1 = *(const bf16x8*)(sKT + (16 * ct + nn) * SB + 32 + qq * 8);
            Sreg[ct] = __builtin_amdgcn_mfma_f32_16x16x32_bf16(av0, kt0, Sreg[ct], 0, 0, 0);
            Sreg[ct] = __builtin_amdgcn_mfma_f32_16x16x32_bf16(av1, kt1, Sreg[ct], 0, 0, 0);
            if (ct == w) {   // chunk Ksum for d-band 16w..16w+15
                float s = 0.f;
#pragma unroll
                for (int j = 0; j < 8; ++j) s += bf2f(kt0[j]) + bf2f(kt1[j]);
                s += __shfl_xor(s, 16);
                s += __shfl_xor(s, 32);
                ksc = s;
            }
        }
        __builtin_amdgcn_s_setprio(0);

#pragma unroll
        for (int r = 0; r < 4; ++r) {
            const int ri = 16 * w + 4 * qq + r;
            const float z = zrow[r] + sZq[ri] + EPSF;
            const float invz = 1.f / z;
#pragma unroll
            for (int ct = 0; ct < 4; ++ct)
                out[gbase + ri * LSTRIDE + 16 * ct + nn] = o[ct][r] * invz;
        }
        __syncthreads();   // S4: all reads of old sST / sVT / sKT / sK done
        // refresh bf16 S mirror + Ksum prefix for next chunk
#pragma unroll
        for (int ct = 0; ct < 4; ++ct)
#pragma unroll
            for (int r = 0; r < 4; ++r)
                sST[(16 * w + 4 * qq + r) * SB + 16 * ct + nn] = (short)f2bf(Sreg[ct][r]);
        if (qq == 0) sKs[16 * w + nn] += ksc;
        qf0 = qfn0;
        qf1 = qfn1;
    }
}

// ---------------------------------------------------------------------------
// Fallback (tiny ws): fully sequential per-sequence scan, fp32, no workspace.
// ---------------------------------------------------------------------------
__global__ __launch_bounds__(64) void k_seq(const float* __restrict__ qin,
                                            const float* __restrict__ kin,
                                            const float* __restrict__ vin,
                                            float* __restrict__ out) {
    const int seq = blockIdx.x;
    const int n = seq / NHEAD, h = seq % NHEAD;
    const int lane = threadIdx.x;
    float Scol[DDIM];
#pragma unroll
    for (int d = 0; d < DDIM; ++d) Scol[d] = 0.0f;
    float kc = 0.0f;
    __shared__ float qk[2 * DDIM];
    int base = (n * LSEQ * NHEAD + h) * DDIM + lane;
    for (int i = 0; i < LSEQ; ++i) {
        float qval = phi(qin[base]);
        float kval = phi(kin[base]);
        float vval = vin[base];
        kc += kval;
        float zp = qval * kc;
#pragma unroll
        for (int off = 32; off > 0; off >>= 1) zp += __shfl_xor(zp, off, 64);
        float z = zp + EPSF;
        qk[2 * lane] = kval;
        qk[2 * lane + 1] = qval;
        __syncthreads();
        const float4* qk4 = (const float4*)qk;
        float acc = 0.0f;
#pragma unroll
        for (int d2 = 0; d2 < DDIM / 2; ++d2) {
            float4 t0 = qk4[d2];
            int d = 2 * d2;
            Scol[d]     += t0.x * vval;  acc += t0.y * Scol[d];
            Scol[d + 1] += t0.z * vval;  acc += t0.w * Scol[d + 1];
        }
        out[base] = acc / z;
        base += LSTRIDE;
        __syncthreads();
    }
}

// ---------------------------------------------------------------------------
extern "C" void kernel_launch(void* const* d_in, const int* in_sizes, int n_in,
                              void* d_out, int out_size, void* d_ws, size_t ws_size,
                              hipStream_t stream) {
    const float* q = (const float*)d_in[0];
    const float* k = (const float*)d_in[1];
    const float* v = (const float*)d_in[2];
    float* out = (float*)d_out;
    float* ws  = (float*)d_ws;

    const size_t need = (size_t)NH * PPART * (DDIM * DDIM + DDIM) * sizeof(float);
    if (ws_size >= need) {
        float* kv   = ws;
        float* ksum = ws + (size_t)NH * PPART * DDIM * DDIM;
        k_psum <<<NH * PPART, 256, 0, stream>>>(k, v, kv, ksum);
        k_scanP<<<NH * 16,     64, 0, stream>>>(kv, ksum);
        k_fused<<<NH * PPART, 256, 0, stream>>>(q, k, v, kv, ksum, out);
    } else {
        k_seq<<<NH, 64, 0, stream>>>(q, k, v, out);
    }
}

// Round 4
// 220.204 us; speedup vs baseline: 1.3509x; 1.1497x over previous
//
#include <hip/hip_runtime.h>

// Causal linear attention (elu+1 feature map) — single-staging 3-kernel scheme.
// N=4, L=4096, H=12, D=M=64.  L split into 16 partitions of 256 rows (4 chunks
// of 64).  K/V are staged exactly ONCE (in k_pass1):
//   k_pass1: per partition, walk 4 chunks with S_local starting at 0:
//            A = Qf Kf^T (masked); O_loc = Amask V + Qf S_loc;
//            z_loc = rowsum(A) + Qf.Ksum_loc;  S_loc += KV^T(chunk).
//            Writes UNNORMALIZED O_loc to out, z_loc to ws, and publishes the
//            partition totals (S_loc, Ksum_loc) for the scan.
//   k_scanP: exclusive prefix scan of partition totals (tiny).
//   k_fix  : per chunk: out = (O_loc + Qf S_p) / (z_loc + Qf.Ks_p + eps).
//            O_loc is loaded straight into the MFMA C operand.
// vs the old scheme this deletes k_psum entirely (the second staging of K/V,
// ~48us of latency-bound phi/transpose/LDS work) at the cost of re-reading
// q/out in the cheap streaming k_fix.
// NOTE: no __launch_bounds__ min-waves arg anywhere — rounds 2/3 proved it
// forces VGPR=64 and spills (~+80MB scratch writes, 2x slowdown).

#define NBATCH 4
#define LSEQ   4096
#define NHEAD  12
#define DDIM   64
#define LSTRIDE (NHEAD * DDIM)
#define NH     (NBATCH * NHEAD)
#define EPSF   1e-6f
#define CHUNK  64
#define NUMC   (LSEQ / CHUNK)
#define PPART  16               // partitions per sequence
#define CPP    (NUMC / PPART)   // chunks per partition = 4
#define SB     72               // LDS row stride in shorts (16B-aligned frags)

typedef __attribute__((ext_vector_type(8))) short bf16x8;
typedef __attribute__((ext_vector_type(4))) float f32x4;

__device__ __forceinline__ float phi(float x) { return x > 0.f ? x + 1.f : __expf(x); }
__device__ __forceinline__ float4 phi4(float4 x) {
    float4 r = {phi(x.x), phi(x.y), phi(x.z), phi(x.w)};
    return r;
}

__device__ __forceinline__ unsigned short f2bf(float x) {
    union { float f; unsigned u; } v; v.f = x;
    unsigned r = v.u + 0x7fffu + ((v.u >> 16) & 1u);   // RNE
    return (unsigned short)(r >> 16);
}
__device__ __forceinline__ float bf2f(short s) {
    union { float f; unsigned u; } v; v.u = ((unsigned)(unsigned short)s) << 16;
    return v.f;
}
__device__ __forceinline__ uint2 pack4(float4 a) {
    uint2 r;
    r.x = (unsigned)f2bf(a.x) | ((unsigned)f2bf(a.y) << 16);
    r.y = (unsigned)f2bf(a.z) | ((unsigned)f2bf(a.w) << 16);
    return r;
}
__device__ __forceinline__ bf16x8 packbf8(float4 a, float4 b) {
    union { bf16x8 v; uint2 u[2]; } r;
    r.u[0] = pack4(a);
    r.u[1] = pack4(b);
    return r.v;
}

// 4x4 fp32 transpose among lanes {lane^16, lane^32}.
__device__ __forceinline__ float4 xpose4(float4 x, int lane) {
    const bool b0 = (lane >> 4) & 1, b1 = (lane >> 5) & 1;
    float s0 = b0 ? x.x : x.y;
    float s1 = b0 ? x.z : x.w;
    s0 = __shfl_xor(s0, 16);
    s1 = __shfl_xor(s1, 16);
    float4 y;
    if (b0) { y.x = s0;  y.y = x.y; y.z = s1;  y.w = x.w; }
    else    { y.x = x.x; y.y = s0;  y.z = x.z; y.w = s1;  }
    float t0 = b1 ? y.x : y.z;
    float t1 = b1 ? y.y : y.w;
    t0 = __shfl_xor(t0, 32);
    t1 = __shfl_xor(t1, 32);
    float4 z;
    if (b1) { z.x = t0;  z.y = t1;  z.z = y.z; z.w = y.w; }
    else    { z.x = y.x; z.y = y.y; z.z = t0;  z.w = t1;  }
    return z;
}

// ---------------------------------------------------------------------------
// Kernel 1: per-partition walk with local S (starts at 0).  Writes
// unnormalized O_loc + z_loc, publishes partition totals.
// ---------------------------------------------------------------------------
__global__ __launch_bounds__(256) void k_pass1(const float* __restrict__ qin,
                                               const float* __restrict__ kin,
                                               const float* __restrict__ vin,
                                               float* __restrict__ kvws,
                                               float* __restrict__ ksws,
                                               float* __restrict__ zws,
                                               float* __restrict__ out) {
    __shared__ short sK [64 * SB];   // K rows (phi,bf16); reused as Amask
    __shared__ short sKT[64 * SB];   // [d][l]
    __shared__ short sVT[64 * SB];   // [m][l]
    __shared__ short sST[64 * SB];   // [m][d] bf16 mirror of running S_loc^T
    __shared__ float sKs[64];
    __shared__ float sZq[64];

    const int b = blockIdx.x, seq = b / PPART, p = b % PPART;
    const int n0 = seq / NHEAD, h0 = seq % NHEAD;
    const int t = threadIdx.x;
    const int lane = t & 63, w = t >> 6;
    const int nn = lane & 15, qq = lane >> 4;
    const int c4 = nn << 2;

    float4 kreg[4], vreg[4];
    auto LOADKV = [&](int cc) {
        const int gb = ((n0 * LSEQ + (p * CPP + cc) * CHUNK) * NHEAD + h0) * DDIM;
#pragma unroll
        for (int rep = 0; rep < 4; ++rep) {
            const int r16 = rep * 16 + 4 * w + qq;
            kreg[rep] = *(const float4*)(kin + gb + r16 * LSTRIDE + c4);
            vreg[rep] = *(const float4*)(vin + gb + r16 * LSTRIDE + c4);
        }
    };
    auto LOADQ = [&](int cc, bf16x8& o0, bf16x8& o1) {
        const float* qp = qin + ((n0 * LSEQ + (p * CPP + cc) * CHUNK) * NHEAD + h0) * DDIM
                        + (16 * w + nn) * LSTRIDE;
        float4 a = phi4(*(const float4*)(qp + qq * 8));
        float4 bq = phi4(*(const float4*)(qp + qq * 8 + 4));
        float4 cq = phi4(*(const float4*)(qp + 32 + qq * 8));
        float4 dq = phi4(*(const float4*)(qp + 32 + qq * 8 + 4));
        o0 = packbf8(a, bq);
        o1 = packbf8(cq, dq);
    };

    bf16x8 qf0, qf1, qfn0, qfn1;
    LOADKV(0);
    LOADQ(0, qf0, qf1);
    if (t < 64) sKs[t] = 0.f;

    f32x4 Sreg[4] = {{0,0,0,0},{0,0,0,0},{0,0,0,0},{0,0,0,0}};
    float ksTot = 0.f;

    for (int cc = 0; cc < CPP; ++cc) {
        const int gbase = ((n0 * LSEQ + (p * CPP + cc) * CHUNK) * NHEAD + h0) * DDIM;
        // ---- stage chunk into LDS (K rows + K^T + V^T) ----
#pragma unroll
        for (int rep = 0; rep < 4; ++rep) {
            const int row = rep * 16 + 4 * w + qq;
            const int l0 = rep * 16 + 4 * w;
            float4 kp = phi4(kreg[rep]);
            *(uint2*)(sK + row * SB + c4) = pack4(kp);
            float4 kt = xpose4(kp, lane);
            *(uint2*)(sKT + (c4 + qq) * SB + l0) = pack4(kt);
            float4 vt = xpose4(vreg[rep], lane);
            *(uint2*)(sVT + (c4 + qq) * SB + l0) = pack4(vt);
        }
        __syncthreads();   // S1 (also orders sKs init/update vs zq reads)

        // ---- Phase A: A = Qf Kf^T, mask + rowsum; zq from local Ksum prefix ----
        const int rowA = 16 * w + nn;
        float am[4][4];
        float zrow[4] = {0.f, 0.f, 0.f, 0.f};
#pragma unroll
        for (int ct = 0; ct < 4; ++ct) {
            bf16x8 kf0 = *(const bf16x8*)(sK + (16 * ct + nn) * SB + qq * 8);
            bf16x8 kf1 = *(const bf16x8*)(sK + (16 * ct + nn) * SB + 32 + qq * 8);
            f32x4 acc = {0.f, 0.f, 0.f, 0.f};
            acc = __builtin_amdgcn_mfma_f32_16x16x32_bf16(qf0, kf0, acc, 0, 0, 0);
            acc = __builtin_amdgcn_mfma_f32_16x16x32_bf16(qf1, kf1, acc, 0, 0, 0);
#pragma unroll
            for (int r = 0; r < 4; ++r) {
                const int ri = 16 * w + 4 * qq + r, cj = 16 * ct + nn;
                const float mval = (cj <= ri) ? acc[r] : 0.f;
                am[ct][r] = mval;
                zrow[r] += mval;
            }
        }
#pragma unroll
        for (int r = 0; r < 4; ++r) {
            float s = zrow[r];
            s += __shfl_xor(s, 1); s += __shfl_xor(s, 2);
            s += __shfl_xor(s, 4); s += __shfl_xor(s, 8);
            zrow[r] = s;
        }
        float zq = 0.f;
        if (cc) {
#pragma unroll
            for (int j = 0; j < 8; ++j) {
                zq += bf2f(qf0[j]) * sKs[qq * 8 + j];
                zq += bf2f(qf1[j]) * sKs[32 + qq * 8 + j];
            }
            zq += __shfl_xor(zq, 16);
            zq += __shfl_xor(zq, 32);
        }

        __syncthreads();   // S2: K reads + sKs reads done
        if (qq == 0) sZq[16 * w + nn] = zq;
#pragma unroll
        for (int ct = 0; ct < 4; ++ct)
#pragma unroll
            for (int r = 0; r < 4; ++r)
                sK[(16 * w + 4 * qq + r) * SB + 16 * ct + nn] = (short)f2bf(am[ct][r]);
        __syncthreads();   // S3: Amask + sZq visible

        if (cc + 1 < CPP) {           // prefetch next chunk under B/C
            LOADKV(cc + 1);
            LOADQ(cc + 1, qfn0, qfn1);
        }

        // ---- Phases B/C + KV^T accumulate ----
        f32x4 o[4] = {{0,0,0,0},{0,0,0,0},{0,0,0,0},{0,0,0,0}};
        bf16x8 af0 = *(const bf16x8*)(sK + rowA * SB + qq * 8);
        bf16x8 af1 = *(const bf16x8*)(sK + rowA * SB + 32 + qq * 8);
        bf16x8 av0 = *(const bf16x8*)(sVT + rowA * SB + qq * 8);
        bf16x8 av1 = *(const bf16x8*)(sVT + rowA * SB + 32 + qq * 8);
        float ksc = 0.f;
#pragma unroll
        for (int ct = 0; ct < 4; ++ct) {
            bf16x8 vf0 = *(const bf16x8*)(sVT + (16 * ct + nn) * SB + qq * 8);
            bf16x8 vf1 = *(const bf16x8*)(sVT + (16 * ct + nn) * SB + 32 + qq * 8);
            o[ct] = __builtin_amdgcn_mfma_f32_16x16x32_bf16(af0, vf0, o[ct], 0, 0, 0);
            o[ct] = __builtin_amdgcn_mfma_f32_16x16x32_bf16(af1, vf1, o[ct], 0, 0, 0);
            if (cc) {   // S_loc == 0 at cc==0
                bf16x8 sf0 = *(const bf16x8*)(sST + (16 * ct + nn) * SB + qq * 8);
                bf16x8 sf1 = *(const bf16x8*)(sST + (16 * ct + nn) * SB + 32 + qq * 8);
                o[ct] = __builtin_amdgcn_mfma_f32_16x16x32_bf16(qf0, sf0, o[ct], 0, 0, 0);
                o[ct] = __builtin_amdgcn_mfma_f32_16x16x32_bf16(qf1, sf1, o[ct], 0, 0, 0);
            }
            bf16x8 kt0 = *(const bf16x8*)(sKT + (16 * ct + nn) * SB + qq * 8);
            bf16x8 kt1 = *(const bf16x8*)(sKT + (16 * ct + nn) * SB + 32 + qq * 8);
            Sreg[ct] = __builtin_amdgcn_mfma_f32_16x16x32_bf16(av0, kt0, Sreg[ct], 0, 0, 0);
            Sreg[ct] = __builtin_amdgcn_mfma_f32_16x16x32_bf16(av1, kt1, Sreg[ct], 0, 0, 0);
            if (ct == w) {   // chunk Ksum for d-band 16w..16w+15
                float s = 0.f;
#pragma unroll
                for (int j = 0; j < 8; ++j) s += bf2f(kt0[j]) + bf2f(kt1[j]);
                s += __shfl_xor(s, 16);
                s += __shfl_xor(s, 32);
                ksc = s;
            }
        }
        ksTot += ksc;

        // ---- write unnormalized O_loc + z_loc ----
#pragma unroll
        for (int r = 0; r < 4; ++r) {
            const int ri = 16 * w + 4 * qq + r;
            if (nn == 0)
                zws[seq * LSEQ + (p * CPP + cc) * CHUNK + ri] = zrow[r] + sZq[ri];
#pragma unroll
            for (int ct = 0; ct < 4; ++ct)
                out[gbase + ri * LSTRIDE + 16 * ct + nn] = o[ct][r];
        }
        __syncthreads();   // S4: all reads of old sST / sVT / sKT / sK done
        if (cc + 1 < CPP) {
            // refresh bf16 S mirror + Ksum prefix for next chunk
#pragma unroll
            for (int ct = 0; ct < 4; ++ct)
#pragma unroll
                for (int r = 0; r < 4; ++r)
                    sST[(16 * w + 4 * qq + r) * SB + 16 * ct + nn] = (short)f2bf(Sreg[ct][r]);
            if (qq == 0) sKs[16 * w + nn] += ksc;
            qf0 = qfn0;
            qf1 = qfn1;
        }
    }

    // ---- publish partition totals ----
    float* kvb = kvws + (size_t)b * (DDIM * DDIM);
#pragma unroll
    for (int ct = 0; ct < 4; ++ct)
#pragma unroll
        for (int r = 0; r < 4; ++r)
            kvb[(16 * w + 4 * qq + r) * DDIM + 16 * ct + nn] = Sreg[ct][r];
    if (qq == 0) ksws[b * DDIM + 16 * w + nn] = ksTot;
}

// ---------------------------------------------------------------------------
// Kernel 2: exclusive prefix scan over the 16 partitions (loads fully
// unrolled up-front so HBM latency is paid once).
// ---------------------------------------------------------------------------
__global__ __launch_bounds__(64) void k_scanP(float* __restrict__ kv,
                                              float* __restrict__ ksum) {
    const int bid = blockIdx.x;
    const int seq = bid >> 4, part = bid & 15;
    const int t = threadIdx.x;
    float4* base = (float4*)(kv + (size_t)seq * PPART * DDIM * DDIM) + part * 64 + t;
    float4 x[PPART];
#pragma unroll
    for (int c = 0; c < PPART; ++c) x[c] = base[c * (DDIM * DDIM / 4)];
    float4 S = {0.f, 0.f, 0.f, 0.f};
#pragma unroll
    for (int c = 0; c < PPART; ++c) {
        base[c * (DDIM * DDIM / 4)] = S;
        S.x += x[c].x; S.y += x[c].y; S.z += x[c].z; S.w += x[c].w;
    }
    if (part == 0) {
        float* kb = ksum + (size_t)seq * PPART * DDIM + t;
        float xs[PPART];
#pragma unroll
        for (int c = 0; c < PPART; ++c) xs[c] = kb[c * DDIM];
        float s = 0.f;
#pragma unroll
        for (int c = 0; c < PPART; ++c) { kb[c * DDIM] = s; s += xs[c]; }
    }
}

// ---------------------------------------------------------------------------
// Kernel 3: streaming fixup, one block per chunk:
//   out = (O_loc + Qf S_p) / (z_loc + Qf.Ks_p + eps)
// O_loc loads straight into the MFMA C operand.  LDS = 1 tile -> high occ.
// ---------------------------------------------------------------------------
__global__ __launch_bounds__(256) void k_fix(const float* __restrict__ qin,
                                             const float* __restrict__ kvws,
                                             const float* __restrict__ ksws,
                                             const float* __restrict__ zws,
                                             float* __restrict__ out) {
    __shared__ short sST[64 * SB];   // bf16 S_p^T ([m][d] rows)
    __shared__ float sKs[64];
    __shared__ float sZq[64];

    const int cg = blockIdx.x;
    const int seq = cg / NUMC, c = cg % NUMC, p = c / CPP;
    const int n0 = seq / NHEAD, h0 = seq % NHEAD;
    const int t = threadIdx.x;
    const int lane = t & 63, w = t >> 6;
    const int nn = lane & 15, qq = lane >> 4;
    const int c4 = nn << 2;
    const int gbase = ((n0 * LSEQ + c * CHUNK) * NHEAD + h0) * DDIM;

    if (t < 64) sKs[t] = ksws[(seq * PPART + p) * DDIM + t];

    // S_p rows -> bf16 LDS
    const float* Sg = kvws + (size_t)(seq * PPART + p) * (DDIM * DDIM);
#pragma unroll
    for (int rep = 0; rep < 4; ++rep) {
        const int row = rep * 16 + 4 * w + qq;
        float4 sv = *(const float4*)(Sg + row * DDIM + c4);
        *(uint2*)(sST + row * SB + c4) = pack4(sv);
    }

    // Qf rows (direct, same phi+pack as pass1)
    const float* qp = qin + gbase + (16 * w + nn) * LSTRIDE;
    float4 a  = phi4(*(const float4*)(qp + qq * 8));
    float4 bq = phi4(*(const float4*)(qp + qq * 8 + 4));
    float4 cq = phi4(*(const float4*)(qp + 32 + qq * 8));
    float4 dq = phi4(*(const float4*)(qp + 32 + qq * 8 + 4));
    bf16x8 qf0 = packbf8(a, bq);
    bf16x8 qf1 = packbf8(cq, dq);

    // O_loc in accumulator layout (C operand) + z_loc per row
    f32x4 o[4];
    float zl[4];
#pragma unroll
    for (int r = 0; r < 4; ++r) {
        const int ri = 16 * w + 4 * qq + r;
        zl[r] = zws[seq * LSEQ + c * CHUNK + ri];
#pragma unroll
        for (int ct = 0; ct < 4; ++ct)
            o[ct][r] = out[gbase + ri * LSTRIDE + 16 * ct + nn];
    }
    __syncthreads();   // S1: sST + sKs ready

    // zq = Qf . Ks_p (row 16w+nn)
    float zq = 0.f;
#pragma unroll
    for (int j = 0; j < 8; ++j) {
        zq += bf2f(qf0[j]) * sKs[qq * 8 + j];
        zq += bf2f(qf1[j]) * sKs[32 + qq * 8 + j];
    }
    zq += __shfl_xor(zq, 16);
    zq += __shfl_xor(zq, 32);
    if (qq == 0) sZq[16 * w + nn] = zq;

    // o += Qf S_p
#pragma unroll
    for (int ct = 0; ct < 4; ++ct) {
        bf16x8 sf0 = *(const bf16x8*)(sST + (16 * ct + nn) * SB + qq * 8);
        bf16x8 sf1 = *(const bf16x8*)(sST + (16 * ct + nn) * SB + 32 + qq * 8);
        o[ct] = __builtin_amdgcn_mfma_f32_16x16x32_bf16(qf0, sf0, o[ct], 0, 0, 0);
        o[ct] = __builtin_amdgcn_mfma_f32_16x16x32_bf16(qf1, sf1, o[ct], 0, 0, 0);
    }
    __syncthreads();   // S2: sZq visible

#pragma unroll
    for (int r = 0; r < 4; ++r) {
        const int ri = 16 * w + 4 * qq + r;
        const float z = zl[r] + sZq[ri] + EPSF;
        const float invz = 1.f / z;
#pragma unroll
        for (int ct = 0; ct < 4; ++ct)
            out[gbase + ri * LSTRIDE + 16 * ct + nn] = o[ct][r] * invz;
    }
}

// ---------------------------------------------------------------------------
// Fallback (tiny ws): fully sequential per-sequence scan, fp32, no workspace.
// ---------------------------------------------------------------------------
__global__ __launch_bounds__(64) void k_seq(const float* __restrict__ qin,
                                            const float* __restrict__ kin,
                                            const float* __restrict__ vin,
                                            float* __restrict__ out) {
    const int seq = blockIdx.x;
    const int n = seq / NHEAD, h = seq % NHEAD;
    const int lane = threadIdx.x;
    float Scol[DDIM];
#pragma unroll
    for (int d = 0; d < DDIM; ++d) Scol[d] = 0.0f;
    float kc = 0.0f;
    __shared__ float qk[2 * DDIM];
    int base = (n * LSEQ * NHEAD + h) * DDIM + lane;
    for (int i = 0; i < LSEQ; ++i) {
        float qval = phi(qin[base]);
        float kval = phi(kin[base]);
        float vval = vin[base];
        kc += kval;
        float zp = qval * kc;
#pragma unroll
        for (int off = 32; off > 0; off >>= 1) zp += __shfl_xor(zp, off, 64);
        float z = zp + EPSF;
        qk[2 * lane] = kval;
        qk[2 * lane + 1] = qval;
        __syncthreads();
        const float4* qk4 = (const float4*)qk;
        float acc = 0.0f;
#pragma unroll
        for (int d2 = 0; d2 < DDIM / 2; ++d2) {
            float4 t0 = qk4[d2];
            int d = 2 * d2;
            Scol[d]     += t0.x * vval;  acc += t0.y * Scol[d];
            Scol[d + 1] += t0.z * vval;  acc += t0.w * Scol[d + 1];
        }
        out[base] = acc / z;
        base += LSTRIDE;
        __syncthreads();
    }
}

// ---------------------------------------------------------------------------
extern "C" void kernel_launch(void* const* d_in, const int* in_sizes, int n_in,
                              void* d_out, int out_size, void* d_ws, size_t ws_size,
                              hipStream_t stream) {
    const float* q = (const float*)d_in[0];
    const float* k = (const float*)d_in[1];
    const float* v = (const float*)d_in[2];
    float* out = (float*)d_out;
    float* ws  = (float*)d_ws;

    const size_t need = ((size_t)NH * PPART * (DDIM * DDIM + DDIM)
                        + (size_t)NH * LSEQ) * sizeof(float);
    if (ws_size >= need) {
        float* kv   = ws;
        float* ksum = kv + (size_t)NH * PPART * DDIM * DDIM;
        float* zws  = ksum + (size_t)NH * PPART * DDIM;
        k_pass1<<<NH * PPART, 256, 0, stream>>>(q, k, v, kv, ksum, zws, out);
        k_scanP<<<NH * 16,     64, 0, stream>>>(kv, ksum);
        k_fix  <<<NH * NUMC,  256, 0, stream>>>(q, kv, ksum, zws, out);
    } else {
        k_seq<<<NH, 64, 0, stream>>>(q, k, v, out);
    }
}